// Round 10
// baseline (1232.265 us; speedup 1.0000x reference)
//
#include <hip/hip_runtime.h>
#include <hip/hip_bf16.h>

// Problem constants (fixed by setup_inputs)
#define NQ   2048
#define NK   2048
#define EMB  64
#define GRP  16
#define FEAT 256

typedef __bf16 bf16x8 __attribute__((ext_vector_type(8)));
typedef __bf16 bf16x4 __attribute__((ext_vector_type(4)));
typedef float  f32x4  __attribute__((ext_vector_type(4)));

#define MFMA(a, b, c) __builtin_amdgcn_mfma_f32_16x16x32_bf16((a), (b), (c), 0, 0, 0)

typedef __attribute__((address_space(3))) unsigned int  lds_u32;
typedef __attribute__((address_space(1))) unsigned int  glb_u32;

static __device__ __forceinline__ bf16x8 cvt8(float4 a, float4 b) {
    bf16x8 r;
    r[0] = (__bf16)a.x; r[1] = (__bf16)a.y; r[2] = (__bf16)a.z; r[3] = (__bf16)a.w;
    r[4] = (__bf16)b.x; r[5] = (__bf16)b.y; r[6] = (__bf16)b.z; r[7] = (__bf16)b.w;
    return r;
}

// ---------------------------------------------------------------------------
// prep_small: fused {prep_roiT | prep_cast | prep_qk | flag-zero}.
// [0,128) roiT | [128,640) cast | [640,1664) qk | [1664] zero flags.
__launch_bounds__(256, 2)
__global__ void prep_small(const float* __restrict__ roi,
                           const float* __restrict__ fc2w,
                           const float* __restrict__ fc2b,
                           const float* __restrict__ fc3w,
                           const float* __restrict__ fc3b,
                           const float* __restrict__ cw,
                           __bf16* __restrict__ roiT,
                           __bf16* __restrict__ convwb,
                           __bf16* __restrict__ qb,
                           __bf16* __restrict__ kb,
                           int* __restrict__ flags) {
    __shared__ float tile[64][65];
    const int b   = blockIdx.x;
    const int tid = threadIdx.x;

    if (b < 128) {
        // ---- roi (2048x256 f32) -> roiT (256x2048 bf16) ----
        const int m0 = (b >> 2) * 64, c0 = (b & 3) * 64;
        const int tr = tid >> 4, tc = tid & 15;
#pragma unroll
        for (int ch = 0; ch < 4; ++ch) {
            int r = ch * 16 + tr;
            float4 v = *(const float4*)(roi + (m0 + r) * 256 + c0 + tc * 4);
            tile[r][tc * 4 + 0] = v.x; tile[r][tc * 4 + 1] = v.y;
            tile[r][tc * 4 + 2] = v.z; tile[r][tc * 4 + 3] = v.w;
        }
        __syncthreads();
#pragma unroll
        for (int ch = 0; ch < 4; ++ch) {
            int crow = ch * 16 + tr;
            int mm = tc * 4;
            bf16x4 o;
            o[0] = (__bf16)tile[mm + 0][crow]; o[1] = (__bf16)tile[mm + 1][crow];
            o[2] = (__bf16)tile[mm + 2][crow]; o[3] = (__bf16)tile[mm + 3][crow];
            *(bf16x4*)(roiT + (c0 + crow) * 2048 + m0 + mm) = o;
        }
    } else if (b < 640) {
        // ---- conv_w f32 -> bf16 ----
        const int cb = b - 128;
        for (int i = cb * 256 + tid; i < 262144; i += 512 * 256) {
            float4 v = ((const float4*)cw)[i];
            bf16x4 o;
            o[0] = (__bf16)v.x; o[1] = (__bf16)v.y; o[2] = (__bf16)v.z; o[3] = (__bf16)v.w;
            ((bf16x4*)convwb)[i] = o;
        }
    } else if (b < 1664) {
        // ---- q/k projection ----
        const int qi = b - 640;
        const int x  = qi & 511;
        const int isK = qi >> 9;
        const float* W    = isK ? fc3w : fc2w;
        const float* bias = isK ? fc3b : fc2b;
        __bf16*      out  = isK ? kb   : qb;
        const int l = tid & 63, wid = tid >> 6;
        const int n0 = (x >> 2) * 16;
        const int dmB = (x & 3) * 256 + wid * 64;
        const int lr = l & 15, lk = l >> 4;
        f32x4 acc[4];
#pragma unroll
        for (int i = 0; i < 4; ++i) acc[i] = (f32x4){0.f, 0.f, 0.f, 0.f};
        for (int k0 = 0; k0 < 256; k0 += 32) {
            const float* ap = roi + (n0 + lr) * 256 + k0 + lk * 8;
            bf16x8 af = cvt8(*(const float4*)ap, *(const float4*)(ap + 4));
#pragma unroll
            for (int cf = 0; cf < 4; ++cf) {
                const float* bp = W + (dmB + cf * 16 + lr) * 256 + k0 + lk * 8;
                acc[cf] = MFMA(af, cvt8(*(const float4*)bp, *(const float4*)(bp + 4)), acc[cf]);
            }
        }
#pragma unroll
        for (int cf = 0; cf < 4; ++cf) {
            int dm = dmB + cf * 16 + lr;
            float bv = bias[dm];
            int g = dm >> 6, d = dm & 63;
#pragma unroll
            for (int ri = 0; ri < 4; ++ri) {
                int n = n0 + lk * 4 + ri;
                out[(g * 2048 + n) * 64 + d] = (__bf16)(acc[cf][ri] + bv);
            }
        }
    } else {
        // ---- zero the producer-consumer flags: 256 chunks x 16 tiles x 2 ----
        for (int i = tid; i < 8192; i += 256) flags[i] = 0;
    }
}

// ---------------------------------------------------------------------------
// relation_attn (producer-consumer fused w): 512 blocks x 256 thr, 2/CU.
// Pair = (bid, bid^8): same n0-chunk, same XCD under both round-robin and
// chunked block->XCD mappings (bit3 flip preserves bid&7 and bid/64).
// Each block produces, ONE TILE AHEAD, the w slice for its 8 queries x all
// 16 groups x its m-half (ghalf*64 of the 128-key tile), stores to global wg
// (L2 relay), publishes a per-tile flag (device-scope atomic), and consumes
// both halves (own + partner, L2-hot) in extraction. Publish-then-spin =>
// deadlock-free; full residency (VGPR<=256 via (256,2), LDS 80KiB) => all
// 512 blocks resident. pe (1.07GB) streams concurrently with attn compute.
// LDS (80 KiB): roi [wid][2 hi][64 row][128B] chunk^row&7 | p [64][128] at 64K.
#define P_BASE 65536
__launch_bounds__(256, 2)
__global__ void relation_attn(const float* __restrict__ pe,
                              const float* __restrict__ fc1w,
                              const float* __restrict__ fc1b,
                              const __bf16* __restrict__ qb,
                              const __bf16* __restrict__ kb,
                              const __bf16* __restrict__ roiT,
                              __bf16* __restrict__ wg,
                              int* __restrict__ flags,
                              __bf16* __restrict__ flat) {
    __shared__ __align__(16) unsigned char smem[81920];
    const int tid = threadIdx.x;
    const int l   = tid & 63;
    const int wid = tid >> 6;          // wave 0..3
    const int bid = blockIdx.x;
    const int ghalf = (bid >> 3) & 1;  // group half AND produced m-half
    const int chunk = ((bid >> 4) << 3) | (bid & 7);   // 0..255
    const int n0  = chunk * 8;
    const int lr  = l & 15;
    const int lk  = l >> 4;
    const int gh  = lk >> 1;
    const int nqh = lk & 1;            // n-half (n2 = nqh*4 + ri)
    const int g2  = ghalf * 8 + wid * 2;
    const int gA  = g2 + gh;

    // q A-frags: rows r -> n = r&7
    bf16x8 qa[2][2];
#pragma unroll
    for (int gi = 0; gi < 2; ++gi)
#pragma unroll
        for (int s = 0; s < 2; ++s)
            qa[gi][s] = *(const bf16x8*)(qb + (long)((g2 + gi) * 2048 + n0 + (lr & 7)) * 64 + s * 32 + lk * 8);

    // fc1 B-frags (rows g = lr) + bias, for w production
    bf16x8 fcB[2];
#pragma unroll
    for (int s = 0; s < 2; ++s) {
        const float* p = fc1w + lr * 64 + s * 32 + lk * 8;
        fcB[s] = cvt8(*(const float4*)p, *(const float4*)(p + 4));
    }
    const float wbias = fc1b[lr];

    f32x4 acc[16];
#pragma unroll
    for (int i = 0; i < 16; ++i) acc[i] = (f32x4){0.f, 0.f, 0.f, 0.f};
    float dsum[4] = {0.f, 0.f, 0.f, 0.f};

    // per-lane w base: row (n0+n2)*16+gA, col lr; ri stride = 16*2048 elements
    const __bf16* wptr = wg + (long)((n0 + (nqh << 2)) * 16 + gA) * 2048 + lr;
    int* flg = flags + chunk * 32;     // [tile 16][half 2]

    // ---- prologue: produce own m-half of w for tile 0 ----
    {
        const int mb = ghalf * 64;
#pragma unroll
        for (int j = 0; j < 2; ++j) {
            const long nq = n0 + wid * 2 + j;
            const float* pb = pe + (nq * 2048 + mb + lr) * 64 + lk * 8;
            __bf16* ob = wg + (nq * 16 + lr) * 2048 + mb + lk * 4;
#pragma unroll
            for (int mf = 0; mf < 4; ++mf) {
                const float* pr = pb + mf * 16 * 64;
                f32x4 c = (f32x4){0.f, 0.f, 0.f, 0.f};
                c = MFMA(cvt8(*(const float4*)(pr),      *(const float4*)(pr + 4)),  fcB[0], c);
                c = MFMA(cvt8(*(const float4*)(pr + 32), *(const float4*)(pr + 36)), fcB[1], c);
                bf16x4 o;
#pragma unroll
                for (int ri = 0; ri < 4; ++ri)
                    o[ri] = (__bf16)fmaxf(fmaxf(c[ri] + wbias, 0.f), 1e-6f);
                *(bf16x4*)(ob + mf * 16) = o;
            }
        }
    }

    for (int t = 0; t < 16; ++t) {
        const int m0t = t * 128;
        __syncthreads();               // A: prev PV done; w(t) stores drained

        // ---- publish own half of tile t (stores drained at A) ----
        if (tid == 0) {
            __threadfence();
            __hip_atomic_store(flg + t * 2 + ghalf, 1,
                               __ATOMIC_RELEASE, __HIP_MEMORY_SCOPE_AGENT);
        }

        // ---- stage roi tile [256 rows][128 keys] via global_load_lds ----
        {
            const int crow = l >> 3, slot = l & 7;
#pragma unroll
            for (int i = 0; i < 16; ++i) {
                int row  = wid * 64 + (i & 7) * 8 + crow;
                int D    = ((i >> 3) << 3) | (slot ^ (row & 7));
                const __bf16* gp = roiT + row * 2048 + m0t + D * 8;
                __builtin_amdgcn_global_load_lds(
                    (const glb_u32*)(const void*)gp,
                    (lds_u32*)(void*)(smem + wid * 16384 + i * 1024), 16, 0, 0);
            }
        }

        // ---- produce own m-half of w for tile t+1 (drains at next A) ----
        if (t < 15) {
            const int mb = (t + 1) * 128 + ghalf * 64;
#pragma unroll
            for (int j = 0; j < 2; ++j) {
                const long nq = n0 + wid * 2 + j;
                const float* pb = pe + (nq * 2048 + mb + lr) * 64 + lk * 8;
                __bf16* ob = wg + (nq * 16 + lr) * 2048 + mb + lk * 4;
#pragma unroll
                for (int mf = 0; mf < 4; ++mf) {
                    const float* pr = pb + mf * 16 * 64;
                    f32x4 c = (f32x4){0.f, 0.f, 0.f, 0.f};
                    c = MFMA(cvt8(*(const float4*)(pr),      *(const float4*)(pr + 4)),  fcB[0], c);
                    c = MFMA(cvt8(*(const float4*)(pr + 32), *(const float4*)(pr + 36)), fcB[1], c);
                    bf16x4 o;
#pragma unroll
                    for (int ri = 0; ri < 4; ++ri)
                        o[ri] = (__bf16)fmaxf(fmaxf(c[ri] + wbias, 0.f), 1e-6f);
                    *(bf16x4*)(ob + mf * 16) = o;
                }
            }
        }

        // ---- wait for partner's half of tile t ----
        if (tid == 0) {
            while (__hip_atomic_load(flg + t * 2 + (ghalf ^ 1),
                                     __ATOMIC_ACQUIRE, __HIP_MEMORY_SCOPE_AGENT) == 0)
                __builtin_amdgcn_s_sleep(8);
        }
        __syncthreads();               // W: partner-ready visible to all threads

        // ---- two 64-key halves: w loads (L2-hot) + QK + extraction ----
#pragma unroll
        for (int h = 0; h < 2; ++h) {
            const int mb = m0t + h * 64;

            float wlv[4][4];
#pragma unroll
            for (int mf = 0; mf < 4; ++mf)
#pragma unroll
                for (int ri = 0; ri < 4; ++ri)
                    wlv[mf][ri] = (float)wptr[(long)ri * 32768 + mb + mf * 16];

            __builtin_amdgcn_s_setprio(1);
            f32x4 a0[4], a1[4];
#pragma unroll
            for (int mf = 0; mf < 4; ++mf) {
                const __bf16* kp = kb + (long)(g2 * 2048 + mb + mf * 16 + lr) * 64 + lk * 8;
                bf16x8 k0 = *(const bf16x8*)(kp);
                bf16x8 k1 = *(const bf16x8*)(kp + 32);
                f32x4 z = (f32x4){0.f, 0.f, 0.f, 0.f};
                z = MFMA(qa[0][0], k0, z);
                z = MFMA(qa[0][1], k1, z);
                a0[mf] = z;
            }
#pragma unroll
            for (int mf = 0; mf < 4; ++mf) {
                const __bf16* kp = kb + (long)((g2 + 1) * 2048 + mb + mf * 16 + lr) * 64 + lk * 8;
                bf16x8 k0 = *(const bf16x8*)(kp);
                bf16x8 k1 = *(const bf16x8*)(kp + 32);
                f32x4 z = (f32x4){0.f, 0.f, 0.f, 0.f};
                z = MFMA(qa[1][0], k0, z);
                z = MFMA(qa[1][1], k1, z);
                a1[mf] = z;
            }
            __builtin_amdgcn_s_setprio(0);

            // extraction: p = w * exp(aff/8)
#pragma unroll
            for (int mf = 0; mf < 4; ++mf) {
                int mm = h * 64 + mf * 16 + lr;                // 0..127
#pragma unroll
                for (int ri = 0; ri < 4; ++ri) {
                    float a = gh ? a1[mf][ri] : a0[mf][ri];
                    int n2 = (nqh << 2) + ri;
                    float pv = wlv[mf][ri] * __expf(a * 0.125f);
                    dsum[ri] += pv;
                    int rp = ((gA & 7) << 3) + n2;
                    int poff = (rp << 8) + ((mm ^ (n2 << 3)) << 1);
                    *(__bf16*)(smem + P_BASE + poff) = (__bf16)pv;
                }
            }
        }

        __syncthreads();               // C: p ready + roi gload_lds drained

        // ---- phase PV: acc += p . roi  (16 rows, 128 keys, 256 cols) ----
        {
            const int rpA = wid * 16 + lr;
            const int QA = (rpA & 7) << 3;
            __builtin_amdgcn_s_setprio(1);
#pragma unroll
            for (int s = 0; s < 4; ++s) {
                bf16x8 pA = *(const bf16x8*)(smem + P_BASE + (rpA << 8)
                                             + (((s * 32 + lk * 8) ^ QA) << 1));
                const int c4 = s * 4 + lk;                     // chunk 0..15
#pragma unroll
                for (int cf = 0; cf < 16; ++cf) {
                    int r = cf * 16 + lr;
                    bf16x8 rB = *(const bf16x8*)(smem
                        + (((r >> 6) * 2 + (c4 >> 3)) << 13)
                        + ((r & 63) << 7)
                        + ((((c4 & 7) ^ (r & 7))) << 4));
                    acc[cf] = MFMA(pA, rB, acc[cf]);
                }
            }
            __builtin_amdgcn_s_setprio(0);
        }
    }

    // ---- epilogue: denominators in registers (lane roles match PV) ----
    float inv[4];
#pragma unroll
    for (int ri = 0; ri < 4; ++ri) {
        float v = dsum[ri];
        v += __shfl_xor(v, 1); v += __shfl_xor(v, 2);
        v += __shfl_xor(v, 4); v += __shfl_xor(v, 8);
        inv[ri] = 1.0f / v;            // den(gA, nqh*4+ri)
    }
#pragma unroll
    for (int cf = 0; cf < 16; ++cf) {
        int c = cf * 16 + lr;
#pragma unroll
        for (int ri = 0; ri < 4; ++ri) {
            int n2 = (nqh << 2) + ri;
            flat[(long)(n0 + n2) * 4096 + gA * 256 + c] = (__bf16)(acc[cf][ri] * inv[ri]);
        }
    }
}

// ---------------------------------------------------------------------------
// out(2048x256 f32) = flat(2048x4096 bf16) @ conv_w(256x4096 bf16)^T + conv_b
__launch_bounds__(256)
__global__ void conv_gemm(const __bf16* __restrict__ flat, const __bf16* __restrict__ cw,
                          const float* __restrict__ cb, float* __restrict__ out) {
    const int tid = threadIdx.x, l = tid & 63, wid = tid >> 6;
    const int n0 = (blockIdx.x >> 1) * 16;
    const int j0 = (blockIdx.x & 1) * 128 + wid * 32;
    const int lr = l & 15, lk = l >> 4;
    f32x4 acc[2] = {(f32x4){0.f, 0.f, 0.f, 0.f}, (f32x4){0.f, 0.f, 0.f, 0.f}};
#pragma unroll 4
    for (int k0 = 0; k0 < 4096; k0 += 32) {
        bf16x8 af = *(const bf16x8*)(flat + (long)(n0 + lr) * 4096 + k0 + lk * 8);
#pragma unroll
        for (int cf = 0; cf < 2; ++cf) {
            bf16x8 bfr = *(const bf16x8*)(cw + (long)(j0 + cf * 16 + lr) * 4096 + k0 + lk * 8);
            acc[cf] = MFMA(af, bfr, acc[cf]);
        }
    }
#pragma unroll
    for (int cf = 0; cf < 2; ++cf) {
        int j = j0 + cf * 16 + lr;
        float bv = cb[j];
#pragma unroll
        for (int ri = 0; ri < 4; ++ri)
            out[(n0 + lk * 4 + ri) * 256 + j] = acc[cf][ri] + bv;
    }
}

// ---------------------------------------------------------------------------
extern "C" void kernel_launch(void* const* d_in, const int* in_sizes, int n_in,
                              void* d_out, int out_size, void* d_ws, size_t ws_size,
                              hipStream_t stream) {
    const float* roi  = (const float*)d_in[0];
    const float* pe   = (const float*)d_in[1];
    const float* fc1w = (const float*)d_in[2];
    const float* fc1b = (const float*)d_in[3];
    const float* fc2w = (const float*)d_in[4];
    const float* fc2b = (const float*)d_in[5];
    const float* fc3w = (const float*)d_in[6];
    const float* fc3b = (const float*)d_in[7];
    const float* cw   = (const float*)d_in[8];
    const float* cb   = (const float*)d_in[9];
    float* out = (float*)d_out;

    unsigned char* ws = (unsigned char*)d_ws;
    __bf16* roiT   = (__bf16*)(ws);                         // 1 MiB
    __bf16* convwb = (__bf16*)(ws + (1ull  << 20));         // 2 MiB
    __bf16* qb     = (__bf16*)(ws + (3ull  << 20));         // 4 MiB
    __bf16* kb     = (__bf16*)(ws + (7ull  << 20));         // 4 MiB
    __bf16* flat   = (__bf16*)(ws + (11ull << 20));         // 16 MiB
    __bf16* wg     = (__bf16*)(ws + (27ull << 20));         // 128 MiB relay
    int*    flags  = (int*)  (ws + (156ull << 20));         // 32 KiB

    prep_small<<<1665, 256, 0, stream>>>(roi, fc2w, fc2b, fc3w, fc3b, cw,
                                         roiT, convwb, qb, kb, flags);
    relation_attn<<<512, 256, 0, stream>>>(pe, fc1w, fc1b, qb, kb, roiT,
                                           wg, flags, flat);
    conv_gemm<<<256, 256, 0, stream>>>(flat, convwb, cb, out);
}

// Round 11
// 834.604 us; speedup vs baseline: 1.4765x; 1.4765x over previous
//
#include <hip/hip_runtime.h>
#include <hip/hip_bf16.h>

// Problem constants (fixed by setup_inputs)
#define NQ   2048
#define NK   2048
#define EMB  64
#define GRP  16
#define FEAT 256

typedef __bf16 bf16x8 __attribute__((ext_vector_type(8)));
typedef __bf16 bf16x4 __attribute__((ext_vector_type(4)));
typedef float  f32x4  __attribute__((ext_vector_type(4)));

#define MFMA(a, b, c) __builtin_amdgcn_mfma_f32_16x16x32_bf16((a), (b), (c), 0, 0, 0)

typedef __attribute__((address_space(3))) unsigned int  lds_u32;
typedef __attribute__((address_space(1))) unsigned int  glb_u32;

static __device__ __forceinline__ bf16x8 cvt8(float4 a, float4 b) {
    bf16x8 r;
    r[0] = (__bf16)a.x; r[1] = (__bf16)a.y; r[2] = (__bf16)a.z; r[3] = (__bf16)a.w;
    r[4] = (__bf16)b.x; r[5] = (__bf16)b.y; r[6] = (__bf16)b.z; r[7] = (__bf16)b.w;
    return r;
}

// ---------------------------------------------------------------------------
// prep_all: fused {prep_roiT | prep_cast | prep_qk | w_gemm} via blockIdx
// range dispatch (R7 version).
// Block ranges: [0,128) roiT | [128,640) cast | [640,1664) qk | [1664,9856) w.
__launch_bounds__(256, 2)
__global__ void prep_all(const float* __restrict__ roi,
                         const float* __restrict__ pe,
                         const float* __restrict__ fc1w,
                         const float* __restrict__ fc1b,
                         const float* __restrict__ fc2w,
                         const float* __restrict__ fc2b,
                         const float* __restrict__ fc3w,
                         const float* __restrict__ fc3b,
                         const float* __restrict__ cw,
                         __bf16* __restrict__ roiT,
                         __bf16* __restrict__ convwb,
                         __bf16* __restrict__ qb,
                         __bf16* __restrict__ kb,
                         __bf16* __restrict__ wg) {
    __shared__ float tile[64][65];     // used by the roiT branch only
    const int b   = blockIdx.x;
    const int tid = threadIdx.x;

    if (b < 128) {
        // ---- prep_roiT: roi (2048x256 f32) -> roiT (256x2048 bf16) ----
        const int m0 = (b >> 2) * 64, c0 = (b & 3) * 64;
        const int tr = tid >> 4, tc = tid & 15;
#pragma unroll
        for (int ch = 0; ch < 4; ++ch) {
            int r = ch * 16 + tr;
            float4 v = *(const float4*)(roi + (m0 + r) * 256 + c0 + tc * 4);
            tile[r][tc * 4 + 0] = v.x; tile[r][tc * 4 + 1] = v.y;
            tile[r][tc * 4 + 2] = v.z; tile[r][tc * 4 + 3] = v.w;
        }
        __syncthreads();
#pragma unroll
        for (int ch = 0; ch < 4; ++ch) {
            int crow = ch * 16 + tr;
            int mm = tc * 4;
            bf16x4 o;
            o[0] = (__bf16)tile[mm + 0][crow]; o[1] = (__bf16)tile[mm + 1][crow];
            o[2] = (__bf16)tile[mm + 2][crow]; o[3] = (__bf16)tile[mm + 3][crow];
            *(bf16x4*)(roiT + (c0 + crow) * 2048 + m0 + mm) = o;
        }
    } else if (b < 640) {
        // ---- prep_cast: conv_w f32 -> bf16 ----
        const int cb = b - 128;
        for (int i = cb * 256 + tid; i < 262144; i += 512 * 256) {
            float4 v = ((const float4*)cw)[i];
            bf16x4 o;
            o[0] = (__bf16)v.x; o[1] = (__bf16)v.y; o[2] = (__bf16)v.z; o[3] = (__bf16)v.w;
            ((bf16x4*)convwb)[i] = o;
        }
    } else if (b < 1664) {
        // ---- prep_qk ----
        const int qi = b - 640;
        const int x  = qi & 511;
        const int isK = qi >> 9;
        const float* W    = isK ? fc3w : fc2w;
        const float* bias = isK ? fc3b : fc2b;
        __bf16*      out  = isK ? kb   : qb;
        const int l = tid & 63, wid = tid >> 6;
        const int n0 = (x >> 2) * 16;
        const int dmB = (x & 3) * 256 + wid * 64;
        const int lr = l & 15, lk = l >> 4;
        f32x4 acc[4];
#pragma unroll
        for (int i = 0; i < 4; ++i) acc[i] = (f32x4){0.f, 0.f, 0.f, 0.f};
        for (int k0 = 0; k0 < 256; k0 += 32) {
            const float* ap = roi + (n0 + lr) * 256 + k0 + lk * 8;
            bf16x8 af = cvt8(*(const float4*)ap, *(const float4*)(ap + 4));
#pragma unroll
            for (int cf = 0; cf < 4; ++cf) {
                const float* bp = W + (dmB + cf * 16 + lr) * 256 + k0 + lk * 8;
                acc[cf] = MFMA(af, cvt8(*(const float4*)bp, *(const float4*)(bp + 4)), acc[cf]);
            }
        }
#pragma unroll
        for (int cf = 0; cf < 4; ++cf) {
            int dm = dmB + cf * 16 + lr;
            float bv = bias[dm];
            int g = dm >> 6, d = dm & 63;
#pragma unroll
            for (int ri = 0; ri < 4; ++ri) {
                int n = n0 + lk * 4 + ri;
                out[(g * 2048 + n) * 64 + d] = (__bf16)(acc[cf][ri] + bv);
            }
        }
    } else {
        // ---- w_gemm ----
        const int wb = b - 1664;
        const int l = tid & 63, wid = tid >> 6;
        const int lr = l & 15, lk = l >> 4;
        const long n = wb >> 2;
        const int mbase = (wb & 3) * 512 + wid * 128;

        bf16x8 fcB[2];
#pragma unroll
        for (int s = 0; s < 2; ++s) {
            const float* p = fc1w + lr * 64 + s * 32 + lk * 8;
            fcB[s] = cvt8(*(const float4*)p, *(const float4*)(p + 4));
        }
        const float bias = fc1b[lr];

        const float* pebase = pe + (n * 2048 + mbase + lr) * 64 + lk * 8;
        __bf16* obase = wg + (n * 16 + lr) * 2048 + mbase + lk * 4;

#pragma unroll 4
        for (int it = 0; it < 8; ++it) {
            const float* p0 = pebase + it * 16 * 64;
            f32x4 c = (f32x4){0.f, 0.f, 0.f, 0.f};
            c = MFMA(cvt8(*(const float4*)(p0),      *(const float4*)(p0 + 4)),  fcB[0], c);
            c = MFMA(cvt8(*(const float4*)(p0 + 32), *(const float4*)(p0 + 36)), fcB[1], c);
            bf16x4 o;
#pragma unroll
            for (int ri = 0; ri < 4; ++ri)
                o[ri] = (__bf16)fmaxf(fmaxf(c[ri] + bias, 0.f), 1e-6f);
            *(bf16x4*)(obase + it * 16) = o;
        }
    }
}

// ---------------------------------------------------------------------------
// qk_extract: QK^T + p = w*exp(aff/8) -> pmat[g][n][m] (bf16 HBM) + inv[n][g].
// NO LDS, NO barriers: pure streaming (wg in, p out, kb from L2). 512 blocks
// x 256 thr, block = 8 queries x 8 groups (ghalf) x all 2048 keys. Same XCD
// swizzle as before (kb half + roiT fit per-XCD L2). Block owns all m for its
// (n,g) set -> denominators finish in-register, inv written directly.
__launch_bounds__(256, 2)
__global__ void qk_extract(const __bf16* __restrict__ wg,
                           const __bf16* __restrict__ qb,
                           const __bf16* __restrict__ kb,
                           __bf16* __restrict__ pmat,
                           float* __restrict__ invb) {
    const int tid = threadIdx.x;
    const int l   = tid & 63;
    const int wid = tid >> 6;          // wave 0..3
    const int s_  = ((blockIdx.x & 7) << 6) | (blockIdx.x >> 3);
    const int n0  = (s_ & 255) * 8;
    const int ghalf = s_ >> 8;
    const int lr  = l & 15;
    const int lk  = l >> 4;
    const int gh  = lk >> 1;
    const int nqh = lk & 1;            // n-half (n2 = nqh*4 + ri)
    const int g2  = ghalf * 8 + wid * 2;
    const int gA  = g2 + gh;

    // q A-frags: rows r -> n = r&7
    bf16x8 qa[2][2];
#pragma unroll
    for (int gi = 0; gi < 2; ++gi)
#pragma unroll
        for (int s = 0; s < 2; ++s)
            qa[gi][s] = *(const bf16x8*)(qb + (long)((g2 + gi) * 2048 + n0 + (lr & 7)) * 64 + s * 32 + lk * 8);

    float dsum[4] = {0.f, 0.f, 0.f, 0.f};

    // per-lane w base: row (n0+n2)*16+gA, col lr; ri stride = 16*2048 elements
    const __bf16* wptr = wg + (long)((n0 + (nqh << 2)) * 16 + gA) * 2048 + lr;
    // per-lane p base: [gA][n0 + nqh*4 + ri][m]; ri stride = 2048
    __bf16* pbase = pmat + ((long)gA * 2048 + n0 + (nqh << 2)) * 2048 + lr;

    for (int t = 0; t < 32; ++t) {
        const int m0t = t * 64;

        // ---- w loads (hidden under kb loads + QK MFMA) ----
        float wlv[4][4];
#pragma unroll
        for (int mf = 0; mf < 4; ++mf)
#pragma unroll
            for (int ri = 0; ri < 4; ++ri)
                wlv[mf][ri] = (float)wptr[(long)ri * 32768 + m0t + mf * 16];

        // ---- QK^T for both groups ----
        __builtin_amdgcn_s_setprio(1);
        f32x4 a0[4], a1[4];
#pragma unroll
        for (int mf = 0; mf < 4; ++mf) {
            const __bf16* kp = kb + (long)(g2 * 2048 + m0t + mf * 16 + lr) * 64 + lk * 8;
            bf16x8 k0 = *(const bf16x8*)(kp);
            bf16x8 k1 = *(const bf16x8*)(kp + 32);
            f32x4 z = (f32x4){0.f, 0.f, 0.f, 0.f};
            z = MFMA(qa[0][0], k0, z);
            z = MFMA(qa[0][1], k1, z);
            a0[mf] = z;
        }
#pragma unroll
        for (int mf = 0; mf < 4; ++mf) {
            const __bf16* kp = kb + (long)((g2 + 1) * 2048 + m0t + mf * 16 + lr) * 64 + lk * 8;
            bf16x8 k0 = *(const bf16x8*)(kp);
            bf16x8 k1 = *(const bf16x8*)(kp + 32);
            f32x4 z = (f32x4){0.f, 0.f, 0.f, 0.f};
            z = MFMA(qa[1][0], k0, z);
            z = MFMA(qa[1][1], k1, z);
            a1[mf] = z;
        }
        __builtin_amdgcn_s_setprio(0);

        // ---- extraction: p = w * exp(aff/8) -> global pmat ----
#pragma unroll
        for (int mf = 0; mf < 4; ++mf) {
#pragma unroll
            for (int ri = 0; ri < 4; ++ri) {
                float a = gh ? a1[mf][ri] : a0[mf][ri];
                float pv = wlv[mf][ri] * __expf(a * 0.125f);
                dsum[ri] += pv;
                pbase[(long)ri * 2048 + m0t + mf * 16] = (__bf16)pv;
            }
        }
    }

    // ---- epilogue: denominators in registers -> inv[n][g] ----
#pragma unroll
    for (int ri = 0; ri < 4; ++ri) {
        float v = dsum[ri];
        v += __shfl_xor(v, 1); v += __shfl_xor(v, 2);
        v += __shfl_xor(v, 4); v += __shfl_xor(v, 8);
        if (lr == 0)
            invb[(n0 + (nqh << 2) + ri) * 16 + gA] = 1.0f / v;
    }
}

// ---------------------------------------------------------------------------
// pv_gemm: flat[n][g*256+c] = inv[n][g] * sum_m pmat[g][n][m] * roiT[c][m].
// Pure streaming GEMM in the proven conv_gemm pattern (A = p rows-n,
// B = roiT rows-c, K = 2048, ascending-m chain = same summation order).
// 4096 blocks x 256 thr: (g 16) x (n-block 128) x (c-half 2); wave = 32 c.
__launch_bounds__(256)
__global__ void pv_gemm(const __bf16* __restrict__ pmat,
                        const __bf16* __restrict__ roiT,
                        const float* __restrict__ invb,
                        __bf16* __restrict__ flat) {
    const int tid = threadIdx.x, l = tid & 63, wid = tid >> 6;
    const int g  = blockIdx.x & 15;
    const int nb = (blockIdx.x >> 4) & 127;
    const int ch = blockIdx.x >> 11;
    const int n0 = nb * 16;
    const int j0 = ch * 128 + wid * 32;
    const int lr = l & 15, lk = l >> 4;
    f32x4 acc[2] = {(f32x4){0.f, 0.f, 0.f, 0.f}, (f32x4){0.f, 0.f, 0.f, 0.f}};
    const __bf16* pA = pmat + ((long)g * 2048 + n0 + lr) * 2048 + lk * 8;
#pragma unroll 4
    for (int k0 = 0; k0 < 2048; k0 += 32) {
        bf16x8 af = *(const bf16x8*)(pA + k0);
#pragma unroll
        for (int cf = 0; cf < 2; ++cf) {
            bf16x8 bfr = *(const bf16x8*)(roiT + (long)(j0 + cf * 16 + lr) * 2048 + k0 + lk * 8);
            acc[cf] = MFMA(af, bfr, acc[cf]);
        }
    }
#pragma unroll
    for (int cf = 0; cf < 2; ++cf) {
        int j = j0 + cf * 16 + lr;
#pragma unroll
        for (int ri = 0; ri < 4; ++ri) {
            int n = n0 + lk * 4 + ri;
            flat[(long)n * 4096 + g * 256 + j] = (__bf16)(acc[cf][ri] * invb[n * 16 + g]);
        }
    }
}

// ---------------------------------------------------------------------------
// out(2048x256 f32) = flat(2048x4096 bf16) @ conv_w(256x4096 bf16)^T + conv_b
__launch_bounds__(256)
__global__ void conv_gemm(const __bf16* __restrict__ flat, const __bf16* __restrict__ cw,
                          const float* __restrict__ cb, float* __restrict__ out) {
    const int tid = threadIdx.x, l = tid & 63, wid = tid >> 6;
    const int n0 = (blockIdx.x >> 1) * 16;
    const int j0 = (blockIdx.x & 1) * 128 + wid * 32;
    const int lr = l & 15, lk = l >> 4;
    f32x4 acc[2] = {(f32x4){0.f, 0.f, 0.f, 0.f}, (f32x4){0.f, 0.f, 0.f, 0.f}};
#pragma unroll 4
    for (int k0 = 0; k0 < 4096; k0 += 32) {
        bf16x8 af = *(const bf16x8*)(flat + (long)(n0 + lr) * 4096 + k0 + lk * 8);
#pragma unroll
        for (int cf = 0; cf < 2; ++cf) {
            bf16x8 bfr = *(const bf16x8*)(cw + (long)(j0 + cf * 16 + lr) * 4096 + k0 + lk * 8);
            acc[cf] = MFMA(af, bfr, acc[cf]);
        }
    }
#pragma unroll
    for (int cf = 0; cf < 2; ++cf) {
        int j = j0 + cf * 16 + lr;
        float bv = cb[j];
#pragma unroll
        for (int ri = 0; ri < 4; ++ri)
            out[(n0 + lk * 4 + ri) * 256 + j] = acc[cf][ri] + bv;
    }
}

// ---------------------------------------------------------------------------
extern "C" void kernel_launch(void* const* d_in, const int* in_sizes, int n_in,
                              void* d_out, int out_size, void* d_ws, size_t ws_size,
                              hipStream_t stream) {
    const float* roi  = (const float*)d_in[0];
    const float* pe   = (const float*)d_in[1];
    const float* fc1w = (const float*)d_in[2];
    const float* fc1b = (const float*)d_in[3];
    const float* fc2w = (const float*)d_in[4];
    const float* fc2b = (const float*)d_in[5];
    const float* fc3w = (const float*)d_in[6];
    const float* fc3b = (const float*)d_in[7];
    const float* cw   = (const float*)d_in[8];
    const float* cb   = (const float*)d_in[9];
    float* out = (float*)d_out;

    unsigned char* ws = (unsigned char*)d_ws;
    __bf16* roiT   = (__bf16*)(ws);                         // 1 MiB
    __bf16* convwb = (__bf16*)(ws + (1ull  << 20));         // 2 MiB
    __bf16* qb     = (__bf16*)(ws + (3ull  << 20));         // 4 MiB
    __bf16* kb     = (__bf16*)(ws + (7ull  << 20));         // 4 MiB
    __bf16* flat   = (__bf16*)(ws + (11ull << 20));         // 16 MiB
    __bf16* wg     = (__bf16*)(ws + (27ull << 20));         // 128 MiB
    __bf16* pmat   = (__bf16*)(ws + (160ull << 20));        // 128 MiB
    float*  invb   = (float*) (ws + (292ull << 20));        // 128 KiB

    prep_all<<<9856, 256, 0, stream>>>(roi, pe, fc1w, fc1b, fc2w, fc2b,
                                       fc3w, fc3b, cw,
                                       roiT, convwb, qb, kb, wg);
    qk_extract<<<512, 256, 0, stream>>>(wg, qb, kb, pmat, invb);
    pv_gemm<<<4096, 256, 0, stream>>>(pmat, roiT, invb, flat);
    conv_gemm<<<256, 256, 0, stream>>>(flat, convwb, cb, out);
}

// Round 12
// 510.705 us; speedup vs baseline: 2.4129x; 1.6342x over previous
//
#include <hip/hip_runtime.h>
#include <hip/hip_bf16.h>

// Problem constants (fixed by setup_inputs)
#define NQ   2048
#define NK   2048
#define EMB  64
#define GRP  16
#define FEAT 256

typedef __bf16 bf16x8 __attribute__((ext_vector_type(8)));
typedef __bf16 bf16x4 __attribute__((ext_vector_type(4)));
typedef float  f32x4  __attribute__((ext_vector_type(4)));

#define MFMA(a, b, c) __builtin_amdgcn_mfma_f32_16x16x32_bf16((a), (b), (c), 0, 0, 0)

typedef __attribute__((address_space(3))) unsigned int  lds_u32;
typedef __attribute__((address_space(1))) unsigned int  glb_u32;

static __device__ __forceinline__ bf16x8 cvt8(float4 a, float4 b) {
    bf16x8 r;
    r[0] = (__bf16)a.x; r[1] = (__bf16)a.y; r[2] = (__bf16)a.z; r[3] = (__bf16)a.w;
    r[4] = (__bf16)b.x; r[5] = (__bf16)b.y; r[6] = (__bf16)b.z; r[7] = (__bf16)b.w;
    return r;
}

// ---------------------------------------------------------------------------
// prep_all: fused {prep_roiT | prep_cast | prep_qk | w_gemm} via blockIdx
// range dispatch (R7 version, best).
// Block ranges: [0,128) roiT | [128,640) cast | [640,1664) qk | [1664,9856) w.
__launch_bounds__(256, 2)
__global__ void prep_all(const float* __restrict__ roi,
                         const float* __restrict__ pe,
                         const float* __restrict__ fc1w,
                         const float* __restrict__ fc1b,
                         const float* __restrict__ fc2w,
                         const float* __restrict__ fc2b,
                         const float* __restrict__ fc3w,
                         const float* __restrict__ fc3b,
                         const float* __restrict__ cw,
                         __bf16* __restrict__ roiT,
                         __bf16* __restrict__ convwb,
                         __bf16* __restrict__ qb,
                         __bf16* __restrict__ kb,
                         __bf16* __restrict__ wg) {
    __shared__ float tile[64][65];     // used by the roiT branch only
    const int b   = blockIdx.x;
    const int tid = threadIdx.x;

    if (b < 128) {
        // ---- prep_roiT: roi (2048x256 f32) -> roiT (256x2048 bf16) ----
        const int m0 = (b >> 2) * 64, c0 = (b & 3) * 64;
        const int tr = tid >> 4, tc = tid & 15;
#pragma unroll
        for (int ch = 0; ch < 4; ++ch) {
            int r = ch * 16 + tr;
            float4 v = *(const float4*)(roi + (m0 + r) * 256 + c0 + tc * 4);
            tile[r][tc * 4 + 0] = v.x; tile[r][tc * 4 + 1] = v.y;
            tile[r][tc * 4 + 2] = v.z; tile[r][tc * 4 + 3] = v.w;
        }
        __syncthreads();
#pragma unroll
        for (int ch = 0; ch < 4; ++ch) {
            int crow = ch * 16 + tr;
            int mm = tc * 4;
            bf16x4 o;
            o[0] = (__bf16)tile[mm + 0][crow]; o[1] = (__bf16)tile[mm + 1][crow];
            o[2] = (__bf16)tile[mm + 2][crow]; o[3] = (__bf16)tile[mm + 3][crow];
            *(bf16x4*)(roiT + (c0 + crow) * 2048 + m0 + mm) = o;
        }
    } else if (b < 640) {
        // ---- prep_cast: conv_w f32 -> bf16 ----
        const int cb = b - 128;
        for (int i = cb * 256 + tid; i < 262144; i += 512 * 256) {
            float4 v = ((const float4*)cw)[i];
            bf16x4 o;
            o[0] = (__bf16)v.x; o[1] = (__bf16)v.y; o[2] = (__bf16)v.z; o[3] = (__bf16)v.w;
            ((bf16x4*)convwb)[i] = o;
        }
    } else if (b < 1664) {
        // ---- prep_qk ----
        const int qi = b - 640;
        const int x  = qi & 511;
        const int isK = qi >> 9;
        const float* W    = isK ? fc3w : fc2w;
        const float* bias = isK ? fc3b : fc2b;
        __bf16*      out  = isK ? kb   : qb;
        const int l = tid & 63, wid = tid >> 6;
        const int n0 = (x >> 2) * 16;
        const int dmB = (x & 3) * 256 + wid * 64;
        const int lr = l & 15, lk = l >> 4;
        f32x4 acc[4];
#pragma unroll
        for (int i = 0; i < 4; ++i) acc[i] = (f32x4){0.f, 0.f, 0.f, 0.f};
        for (int k0 = 0; k0 < 256; k0 += 32) {
            const float* ap = roi + (n0 + lr) * 256 + k0 + lk * 8;
            bf16x8 af = cvt8(*(const float4*)ap, *(const float4*)(ap + 4));
#pragma unroll
            for (int cf = 0; cf < 4; ++cf) {
                const float* bp = W + (dmB + cf * 16 + lr) * 256 + k0 + lk * 8;
                acc[cf] = MFMA(af, cvt8(*(const float4*)bp, *(const float4*)(bp + 4)), acc[cf]);
            }
        }
#pragma unroll
        for (int cf = 0; cf < 4; ++cf) {
            int dm = dmB + cf * 16 + lr;
            float bv = bias[dm];
            int g = dm >> 6, d = dm & 63;
#pragma unroll
            for (int ri = 0; ri < 4; ++ri) {
                int n = n0 + lk * 4 + ri;
                out[(g * 2048 + n) * 64 + d] = (__bf16)(acc[cf][ri] + bv);
            }
        }
    } else {
        // ---- w_gemm ----
        const int wb = b - 1664;
        const int l = tid & 63, wid = tid >> 6;
        const int lr = l & 15, lk = l >> 4;
        const long n = wb >> 2;
        const int mbase = (wb & 3) * 512 + wid * 128;

        bf16x8 fcB[2];
#pragma unroll
        for (int s = 0; s < 2; ++s) {
            const float* p = fc1w + lr * 64 + s * 32 + lk * 8;
            fcB[s] = cvt8(*(const float4*)p, *(const float4*)(p + 4));
        }
        const float bias = fc1b[lr];

        const float* pebase = pe + (n * 2048 + mbase + lr) * 64 + lk * 8;
        __bf16* obase = wg + (n * 16 + lr) * 2048 + mbase + lk * 4;

#pragma unroll 4
        for (int it = 0; it < 8; ++it) {
            const float* p0 = pebase + it * 16 * 64;
            f32x4 c = (f32x4){0.f, 0.f, 0.f, 0.f};
            c = MFMA(cvt8(*(const float4*)(p0),      *(const float4*)(p0 + 4)),  fcB[0], c);
            c = MFMA(cvt8(*(const float4*)(p0 + 32), *(const float4*)(p0 + 36)), fcB[1], c);
            bf16x4 o;
#pragma unroll
            for (int ri = 0; ri < 4; ++ri)
                o[ri] = (__bf16)fmaxf(fmaxf(c[ri] + bias, 0.f), 1e-6f);
            *(bf16x4*)(obase + it * 16) = o;
        }
    }
}

// ---------------------------------------------------------------------------
// relation_attn: 256 blocks x 512 thr. Block = 16 queries x 8 groups (ghalf)
// x all 2048 keys. Waves 0-3 own queries n0..n0+8, waves 4-7 own n0+8..n0+16;
// per-wave body is verbatim R6 (2 groups x 8 queries, KVBLK=64).
// LDS = 48 KiB (roi 32K shared by both q-chunks + p 2x8K) -> 3 blocks by LDS;
// VGPR (~124, measured on the R10 variant) <= 128 -> 4 waves/SIMD ->
// 2 blocks/CU = 16 waves/CU, DOUBLE the previous 8. launch_bounds(512,1)
// caps VGPR at 256: no spill possible; worst case (>128 VGPR) it falls back
// to 1 block/CU = today's occupancy.
// LDS layout:
//   [0,32768)      roi tile [c 256][mm 64] bf16, 16B-chunk ^ (c&7) (gload_lds)
//   [32768,49152)  p tile [qh 2][rp=glo*8+n2 64][mm 64] bf16, mm ^ (n2<<3)
#define P_BASE 32768
__launch_bounds__(512, 1)
__global__ void relation_attn(const __bf16* __restrict__ wg,
                              const __bf16* __restrict__ qb,
                              const __bf16* __restrict__ kb,
                              const __bf16* __restrict__ roiT,
                              __bf16* __restrict__ flat) {
    __shared__ __align__(16) unsigned char smem[49152];
    const int tid = threadIdx.x;
    const int l   = tid & 63;
    const int wid = tid >> 6;          // wave 0..7
    // bijective XCD swizzle over 256 blocks: XCDs 0-3 -> ghalf 0, 4-7 -> ghalf 1
    const int s_  = ((blockIdx.x & 7) << 5) | (blockIdx.x >> 3);
    const int n0  = (s_ & 127) * 16;
    const int ghalf = s_ >> 7;         // group half: g in [ghalf*8, ghalf*8+8)
    const int qh  = wid >> 2;          // query sub-chunk 0..1
    const int wp  = wid & 3;           // wave-pair index within chunk
    const int nq0 = n0 + qh * 8;
    const int lr  = l & 15;
    const int lk  = l >> 4;
    const int gh  = lk >> 1;
    const int nqh = lk & 1;            // n-half (n2 = nqh*4 + ri)
    const int g2  = ghalf * 8 + wp * 2;
    const int gA  = g2 + gh;           // extraction/epilogue group

    // q A-frags: rows r -> n = r&7
    bf16x8 qa[2][2];
#pragma unroll
    for (int gi = 0; gi < 2; ++gi)
#pragma unroll
        for (int s = 0; s < 2; ++s)
            qa[gi][s] = *(const bf16x8*)(qb + (long)((g2 + gi) * 2048 + nq0 + (lr & 7)) * 64 + s * 32 + lk * 8);

    f32x4 acc[16];
#pragma unroll
    for (int i = 0; i < 16; ++i) acc[i] = (f32x4){0.f, 0.f, 0.f, 0.f};
    float dsum[4] = {0.f, 0.f, 0.f, 0.f};

    // per-lane w base: row (nq0+n2)*16+gA, col lr; ri stride = 16*2048 elements
    const __bf16* wptr = wg + (long)((nq0 + (nqh << 2)) * 16 + gA) * 2048 + lr;

    for (int t = 0; t < 32; ++t) {
        const int m0t = t * 64;
        __syncthreads();               // A: prev PV LDS reads done

        // ---- stage roi tile via global_load_lds (pre-swizzled source) ----
        // 8 waves cooperatively stage 256 rows x 64 keys (4 chunks/thread)
        {
            const int crow = l >> 3, slot = l & 7;
#pragma unroll
            for (int i = 0; i < 4; ++i) {
                int c = wid * 32 + i * 8 + crow;
                int D = slot ^ (c & 7);
                const __bf16* gp = roiT + c * 2048 + m0t + D * 8;
                __builtin_amdgcn_global_load_lds(
                    (const glb_u32*)(const void*)gp,
                    (lds_u32*)(void*)(smem + wid * 4096 + i * 1024), 16, 0, 0);
            }
        }

        // ---- w loads (global, hidden under kb loads + QK MFMA) ----
        float wlv[4][4];
#pragma unroll
        for (int mf = 0; mf < 4; ++mf)
#pragma unroll
            for (int ri = 0; ri < 4; ++ri)
                wlv[mf][ri] = (float)wptr[(long)ri * 32768 + m0t + mf * 16];

        // ---- QK^T for both groups ----
        __builtin_amdgcn_s_setprio(1);
        f32x4 a0[4], a1[4];
#pragma unroll
        for (int mf = 0; mf < 4; ++mf) {
            const __bf16* kp = kb + (long)(g2 * 2048 + m0t + mf * 16 + lr) * 64 + lk * 8;
            bf16x8 k0 = *(const bf16x8*)(kp);
            bf16x8 k1 = *(const bf16x8*)(kp + 32);
            f32x4 z = (f32x4){0.f, 0.f, 0.f, 0.f};
            z = MFMA(qa[0][0], k0, z);
            z = MFMA(qa[0][1], k1, z);
            a0[mf] = z;
        }
#pragma unroll
        for (int mf = 0; mf < 4; ++mf) {
            const __bf16* kp = kb + (long)((g2 + 1) * 2048 + m0t + mf * 16 + lr) * 64 + lk * 8;
            bf16x8 k0 = *(const bf16x8*)(kp);
            bf16x8 k1 = *(const bf16x8*)(kp + 32);
            f32x4 z = (f32x4){0.f, 0.f, 0.f, 0.f};
            z = MFMA(qa[1][0], k0, z);
            z = MFMA(qa[1][1], k1, z);
            a1[mf] = z;
        }
        __builtin_amdgcn_s_setprio(0);

        // ---- extraction: p = w * exp(aff/8), full wave ----
#pragma unroll
        for (int mf = 0; mf < 4; ++mf) {
            int mm = mf * 16 + lr;
#pragma unroll
            for (int ri = 0; ri < 4; ++ri) {
                float a = gh ? a1[mf][ri] : a0[mf][ri];
                int n2 = (nqh << 2) + ri;
                float pv = wlv[mf][ri] * __expf(a * 0.125f);
                dsum[ri] += pv;
                int rp = ((gA & 7) << 3) + n2;    // local group row in p tile
                int poff = (qh << 13) + (rp << 7) + ((mm ^ (n2 << 3)) << 1);
                *(__bf16*)(smem + P_BASE + poff) = (__bf16)pv;
            }
        }

        __syncthreads();               // C: p ready + roi gload_lds drained

        // ---- phase PV: acc += p . roi  (16 rows = 2 groups x 8 n) ----
        {
            const int rpA = wp * 16 + lr;
            const int QA = (rpA & 7) << 3;
            __builtin_amdgcn_s_setprio(1);
#pragma unroll
            for (int s = 0; s < 2; ++s) {
                bf16x8 pA = *(const bf16x8*)(smem + P_BASE + (qh << 13) + (rpA << 7)
                                             + (((s * 32 + lk * 8) ^ QA) << 1));
#pragma unroll
                for (int cf = 0; cf < 16; ++cf) {
                    int c = cf * 16 + lr;
                    bf16x8 rB = *(const bf16x8*)(smem + c * 128
                                                 + (((s * 4 + lk) ^ (c & 7)) << 4));
                    acc[cf] = MFMA(pA, rB, acc[cf]);
                }
            }
            __builtin_amdgcn_s_setprio(0);
        }
    }

    // ---- epilogue: denominators in registers (lane roles match PV) ----
    float inv[4];
#pragma unroll
    for (int ri = 0; ri < 4; ++ri) {
        float v = dsum[ri];
        v += __shfl_xor(v, 1); v += __shfl_xor(v, 2);
        v += __shfl_xor(v, 4); v += __shfl_xor(v, 8);
        inv[ri] = 1.0f / v;            // den(gA, nqh*4+ri)
    }
#pragma unroll
    for (int cf = 0; cf < 16; ++cf) {
        int c = cf * 16 + lr;
#pragma unroll
        for (int ri = 0; ri < 4; ++ri) {
            int n2 = (nqh << 2) + ri;
            flat[(long)(nq0 + n2) * 4096 + gA * 256 + c] = (__bf16)(acc[cf][ri] * inv[ri]);
        }
    }
}

// ---------------------------------------------------------------------------
// out(2048x256 f32) = flat(2048x4096 bf16) @ conv_w(256x4096 bf16)^T + conv_b
__launch_bounds__(256)
__global__ void conv_gemm(const __bf16* __restrict__ flat, const __bf16* __restrict__ cw,
                          const float* __restrict__ cb, float* __restrict__ out) {
    const int tid = threadIdx.x, l = tid & 63, wid = tid >> 6;
    const int n0 = (blockIdx.x >> 1) * 16;
    const int j0 = (blockIdx.x & 1) * 128 + wid * 32;
    const int lr = l & 15, lk = l >> 4;
    f32x4 acc[2] = {(f32x4){0.f, 0.f, 0.f, 0.f}, (f32x4){0.f, 0.f, 0.f, 0.f}};
#pragma unroll 4
    for (int k0 = 0; k0 < 4096; k0 += 32) {
        bf16x8 af = *(const bf16x8*)(flat + (long)(n0 + lr) * 4096 + k0 + lk * 8);
#pragma unroll
        for (int cf = 0; cf < 2; ++cf) {
            bf16x8 bfr = *(const bf16x8*)(cw + (long)(j0 + cf * 16 + lr) * 4096 + k0 + lk * 8);
            acc[cf] = MFMA(af, bfr, acc[cf]);
        }
    }
#pragma unroll
    for (int cf = 0; cf < 2; ++cf) {
        int j = j0 + cf * 16 + lr;
        float bv = cb[j];
#pragma unroll
        for (int ri = 0; ri < 4; ++ri)
            out[(n0 + lk * 4 + ri) * 256 + j] = acc[cf][ri] + bv;
    }
}

// ---------------------------------------------------------------------------
extern "C" void kernel_launch(void* const* d_in, const int* in_sizes, int n_in,
                              void* d_out, int out_size, void* d_ws, size_t ws_size,
                              hipStream_t stream) {
    const float* roi  = (const float*)d_in[0];
    const float* pe   = (const float*)d_in[1];
    const float* fc1w = (const float*)d_in[2];
    const float* fc1b = (const float*)d_in[3];
    const float* fc2w = (const float*)d_in[4];
    const float* fc2b = (const float*)d_in[5];
    const float* fc3w = (const float*)d_in[6];
    const float* fc3b = (const float*)d_in[7];
    const float* cw   = (const float*)d_in[8];
    const float* cb   = (const float*)d_in[9];
    float* out = (float*)d_out;

    unsigned char* ws = (unsigned char*)d_ws;
    __bf16* roiT   = (__bf16*)(ws);                         // 1 MiB
    __bf16* convwb = (__bf16*)(ws + (1ull  << 20));         // 2 MiB
    __bf16* qb     = (__bf16*)(ws + (3ull  << 20));         // 4 MiB
    __bf16* kb     = (__bf16*)(ws + (7ull  << 20));         // 4 MiB
    __bf16* flat   = (__bf16*)(ws + (11ull << 20));         // 16 MiB
    __bf16* wg     = (__bf16*)(ws + (27ull << 20));         // 128 MiB

    prep_all<<<9856, 256, 0, stream>>>(roi, pe, fc1w, fc1b, fc2w, fc2b,
                                       fc3w, fc3b, cw,
                                       roiT, convwb, qb, kb, wg);
    relation_attn<<<256, 512, 0, stream>>>(wg, qb, kb, roiT, flat);
    conv_gemm<<<256, 256, 0, stream>>>(flat, convwb, cb, out);
}

// Round 13
// 487.710 us; speedup vs baseline: 2.5266x; 1.0471x over previous
//
#include <hip/hip_runtime.h>
#include <hip/hip_bf16.h>

// Problem constants (fixed by setup_inputs)
#define NQ   2048
#define NK   2048
#define EMB  64
#define GRP  16
#define FEAT 256

typedef __bf16 bf16x8 __attribute__((ext_vector_type(8)));
typedef __bf16 bf16x4 __attribute__((ext_vector_type(4)));
typedef float  f32x4  __attribute__((ext_vector_type(4)));

#define MFMA(a, b, c) __builtin_amdgcn_mfma_f32_16x16x32_bf16((a), (b), (c), 0, 0, 0)

typedef __attribute__((address_space(3))) unsigned int  lds_u32;
typedef __attribute__((address_space(1))) unsigned int  glb_u32;

static __device__ __forceinline__ bf16x8 cvt8(float4 a, float4 b) {
    bf16x8 r;
    r[0] = (__bf16)a.x; r[1] = (__bf16)a.y; r[2] = (__bf16)a.z; r[3] = (__bf16)a.w;
    r[4] = (__bf16)b.x; r[5] = (__bf16)b.y; r[6] = (__bf16)b.z; r[7] = (__bf16)b.w;
    return r;
}

// ---------------------------------------------------------------------------
// prep_all: fused {prep_roiT | prep_cast | prep_qk | w_gemm} via blockIdx
// range dispatch. Small preps lead so they drain under the HBM-bound w stream.
// Block ranges: [0,128) roiT | [128,640) cast | [640,1664) qk | [1664,9856) w.
__launch_bounds__(256, 2)
__global__ void prep_all(const float* __restrict__ roi,
                         const float* __restrict__ pe,
                         const float* __restrict__ fc1w,
                         const float* __restrict__ fc1b,
                         const float* __restrict__ fc2w,
                         const float* __restrict__ fc2b,
                         const float* __restrict__ fc3w,
                         const float* __restrict__ fc3b,
                         const float* __restrict__ cw,
                         __bf16* __restrict__ roiT,
                         __bf16* __restrict__ convwb,
                         __bf16* __restrict__ qb,
                         __bf16* __restrict__ kb,
                         __bf16* __restrict__ wg) {
    __shared__ float tile[64][65];     // used by the roiT branch only
    const int b   = blockIdx.x;
    const int tid = threadIdx.x;

    if (b < 128) {
        // ---- prep_roiT: roi (2048x256 f32) -> roiT (256x2048 bf16) ----
        const int m0 = (b >> 2) * 64, c0 = (b & 3) * 64;
        const int tr = tid >> 4, tc = tid & 15;
#pragma unroll
        for (int ch = 0; ch < 4; ++ch) {
            int r = ch * 16 + tr;
            float4 v = *(const float4*)(roi + (m0 + r) * 256 + c0 + tc * 4);
            tile[r][tc * 4 + 0] = v.x; tile[r][tc * 4 + 1] = v.y;
            tile[r][tc * 4 + 2] = v.z; tile[r][tc * 4 + 3] = v.w;
        }
        __syncthreads();
#pragma unroll
        for (int ch = 0; ch < 4; ++ch) {
            int crow = ch * 16 + tr;
            int mm = tc * 4;
            bf16x4 o;
            o[0] = (__bf16)tile[mm + 0][crow]; o[1] = (__bf16)tile[mm + 1][crow];
            o[2] = (__bf16)tile[mm + 2][crow]; o[3] = (__bf16)tile[mm + 3][crow];
            *(bf16x4*)(roiT + (c0 + crow) * 2048 + m0 + mm) = o;
        }
    } else if (b < 640) {
        // ---- prep_cast: conv_w f32 -> bf16 ----
        const int cb = b - 128;
        for (int i = cb * 256 + tid; i < 262144; i += 512 * 256) {
            float4 v = ((const float4*)cw)[i];
            bf16x4 o;
            o[0] = (__bf16)v.x; o[1] = (__bf16)v.y; o[2] = (__bf16)v.z; o[3] = (__bf16)v.w;
            ((bf16x4*)convwb)[i] = o;
        }
    } else if (b < 1664) {
        // ---- prep_qk ----
        const int qi = b - 640;
        const int x  = qi & 511;
        const int isK = qi >> 9;
        const float* W    = isK ? fc3w : fc2w;
        const float* bias = isK ? fc3b : fc2b;
        __bf16*      out  = isK ? kb   : qb;
        const int l = tid & 63, wid = tid >> 6;
        const int n0 = (x >> 2) * 16;
        const int dmB = (x & 3) * 256 + wid * 64;
        const int lr = l & 15, lk = l >> 4;
        f32x4 acc[4];
#pragma unroll
        for (int i = 0; i < 4; ++i) acc[i] = (f32x4){0.f, 0.f, 0.f, 0.f};
        for (int k0 = 0; k0 < 256; k0 += 32) {
            const float* ap = roi + (n0 + lr) * 256 + k0 + lk * 8;
            bf16x8 af = cvt8(*(const float4*)ap, *(const float4*)(ap + 4));
#pragma unroll
            for (int cf = 0; cf < 4; ++cf) {
                const float* bp = W + (dmB + cf * 16 + lr) * 256 + k0 + lk * 8;
                acc[cf] = MFMA(af, cvt8(*(const float4*)bp, *(const float4*)(bp + 4)), acc[cf]);
            }
        }
#pragma unroll
        for (int cf = 0; cf < 4; ++cf) {
            int dm = dmB + cf * 16 + lr;
            float bv = bias[dm];
            int g = dm >> 6, d = dm & 63;
#pragma unroll
            for (int ri = 0; ri < 4; ++ri) {
                int n = n0 + lk * 4 + ri;
                out[(g * 2048 + n) * 64 + d] = (__bf16)(acc[cf][ri] + bv);
            }
        }
    } else {
        // ---- w_gemm ----
        const int wb = b - 1664;
        const int l = tid & 63, wid = tid >> 6;
        const int lr = l & 15, lk = l >> 4;
        const long n = wb >> 2;
        const int mbase = (wb & 3) * 512 + wid * 128;

        bf16x8 fcB[2];
#pragma unroll
        for (int s = 0; s < 2; ++s) {
            const float* p = fc1w + lr * 64 + s * 32 + lk * 8;
            fcB[s] = cvt8(*(const float4*)p, *(const float4*)(p + 4));
        }
        const float bias = fc1b[lr];

        const float* pebase = pe + (n * 2048 + mbase + lr) * 64 + lk * 8;
        __bf16* obase = wg + (n * 16 + lr) * 2048 + mbase + lk * 4;

#pragma unroll 4
        for (int it = 0; it < 8; ++it) {
            const float* p0 = pebase + it * 16 * 64;
            f32x4 c = (f32x4){0.f, 0.f, 0.f, 0.f};
            c = MFMA(cvt8(*(const float4*)(p0),      *(const float4*)(p0 + 4)),  fcB[0], c);
            c = MFMA(cvt8(*(const float4*)(p0 + 32), *(const float4*)(p0 + 36)), fcB[1], c);
            bf16x4 o;
#pragma unroll
            for (int ri = 0; ri < 4; ++ri)
                o[ri] = (__bf16)fmaxf(fmaxf(c[ri] + bias, 0.f), 1e-6f);
            *(bf16x4*)(obase + it * 16) = o;
        }
    }
}

// ---------------------------------------------------------------------------
// relation_attn: block = 8 queries x all 2048 keys x 8 groups (half).
// 512 blocks x 256 thr -> 2 blocks/CU. KVBLK=128: 16 tiles, 32 barriers.
// QK/extraction run in two 64-key halves to keep a0/a1/wlv at [4] (no spill).
// LDS (80 KiB, 2 blocks = 160 KiB = full pool):
//   [0,65536)      roi tile: per-wave region [wid][2 chunk-hi][64 row][128B],
//                  16B-chunk low3 ^ (row&7)  (global_load_lds, preswz source)
//   [65536,81920)  p tile [rp=glo*8+n2 64][mm 128] bf16, mm ^ (n2<<3)
#define P_BASE 65536
__launch_bounds__(256, 2)
__global__ void relation_attn(const __bf16* __restrict__ wg,
                              const __bf16* __restrict__ qb,
                              const __bf16* __restrict__ kb,
                              const __bf16* __restrict__ roiT,
                              __bf16* __restrict__ flat) {
    __shared__ __align__(16) unsigned char smem[81920];
    const int tid = threadIdx.x;
    const int l   = tid & 63;
    const int wid = tid >> 6;          // wave 0..3
    // bijective XCD swizzle (512 blocks, 8 XCDs): s = ghalf*256 + n0idx
    const int s_  = ((blockIdx.x & 7) << 6) | (blockIdx.x >> 3);
    const int n0  = (s_ & 255) * 8;
    const int ghalf = s_ >> 8;
    const int lr  = l & 15;
    const int lk  = l >> 4;
    const int gh  = lk >> 1;
    const int nqh = lk & 1;            // n-half (n2 = nqh*4 + ri)
    const int g2  = ghalf * 8 + wid * 2;
    const int gA  = g2 + gh;

    // q A-frags: rows r -> n = r&7
    bf16x8 qa[2][2];
#pragma unroll
    for (int gi = 0; gi < 2; ++gi)
#pragma unroll
        for (int s = 0; s < 2; ++s)
            qa[gi][s] = *(const bf16x8*)(qb + (long)((g2 + gi) * 2048 + n0 + (lr & 7)) * 64 + s * 32 + lk * 8);

    f32x4 acc[16];
#pragma unroll
    for (int i = 0; i < 16; ++i) acc[i] = (f32x4){0.f, 0.f, 0.f, 0.f};
    float dsum[4] = {0.f, 0.f, 0.f, 0.f};

    // per-lane w base: row (n0+n2)*16+gA, col lr; ri stride = 16*2048 elements
    const __bf16* wptr = wg + (long)((n0 + (nqh << 2)) * 16 + gA) * 2048 + lr;

    for (int t = 0; t < 16; ++t) {
        const int m0t = t * 128;
        __syncthreads();               // A: prev PV LDS reads done

        // ---- stage roi tile [256 rows][128 keys] via global_load_lds ----
        {
            const int crow = l >> 3, slot = l & 7;
#pragma unroll
            for (int i = 0; i < 16; ++i) {
                int row  = wid * 64 + (i & 7) * 8 + crow;      // global roi row
                int D    = ((i >> 3) << 3) | (slot ^ (row & 7)); // src 16B chunk
                const __bf16* gp = roiT + row * 2048 + m0t + D * 8;
                __builtin_amdgcn_global_load_lds(
                    (const glb_u32*)(const void*)gp,
                    (lds_u32*)(void*)(smem + wid * 16384 + i * 1024), 16, 0, 0);
            }
        }

        // ---- two 64-key halves: w loads + QK + extraction ----
#pragma unroll
        for (int h = 0; h < 2; ++h) {
            const int mb = m0t + h * 64;

            // w loads (global; absorbed per R2-R4 evidence)
            float wlv[4][4];
#pragma unroll
            for (int mf = 0; mf < 4; ++mf)
#pragma unroll
                for (int ri = 0; ri < 4; ++ri)
                    wlv[mf][ri] = (float)wptr[(long)ri * 32768 + mb + mf * 16];

            __builtin_amdgcn_s_setprio(1);
            f32x4 a0[4], a1[4];
#pragma unroll
            for (int mf = 0; mf < 4; ++mf) {
                const __bf16* kp = kb + (long)(g2 * 2048 + mb + mf * 16 + lr) * 64 + lk * 8;
                bf16x8 k0 = *(const bf16x8*)(kp);
                bf16x8 k1 = *(const bf16x8*)(kp + 32);
                f32x4 z = (f32x4){0.f, 0.f, 0.f, 0.f};
                z = MFMA(qa[0][0], k0, z);
                z = MFMA(qa[0][1], k1, z);
                a0[mf] = z;
            }
#pragma unroll
            for (int mf = 0; mf < 4; ++mf) {
                const __bf16* kp = kb + (long)((g2 + 1) * 2048 + mb + mf * 16 + lr) * 64 + lk * 8;
                bf16x8 k0 = *(const bf16x8*)(kp);
                bf16x8 k1 = *(const bf16x8*)(kp + 32);
                f32x4 z = (f32x4){0.f, 0.f, 0.f, 0.f};
                z = MFMA(qa[1][0], k0, z);
                z = MFMA(qa[1][1], k1, z);
                a1[mf] = z;
            }
            __builtin_amdgcn_s_setprio(0);

            // extraction: p = w * exp(aff/8)
#pragma unroll
            for (int mf = 0; mf < 4; ++mf) {
                int mm = h * 64 + mf * 16 + lr;                // 0..127
#pragma unroll
                for (int ri = 0; ri < 4; ++ri) {
                    float a = gh ? a1[mf][ri] : a0[mf][ri];
                    int n2 = (nqh << 2) + ri;
                    float pv = wlv[mf][ri] * __expf(a * 0.125f);
                    dsum[ri] += pv;
                    int rp = ((gA & 7) << 3) + n2;
                    int poff = (rp << 8) + ((mm ^ (n2 << 3)) << 1);
                    *(__bf16*)(smem + P_BASE + poff) = (__bf16)pv;
                }
            }
        }

        __syncthreads();               // C: p ready + roi gload_lds drained

        // ---- phase PV: acc += p . roi  (16 rows, 128 keys, 256 cols) ----
        {
            const int rpA = wid * 16 + lr;
            const int QA = (rpA & 7) << 3;
            __builtin_amdgcn_s_setprio(1);
#pragma unroll
            for (int s = 0; s < 4; ++s) {
                bf16x8 pA = *(const bf16x8*)(smem + P_BASE + (rpA << 8)
                                             + (((s * 32 + lk * 8) ^ QA) << 1));
                const int c4 = s * 4 + lk;                     // chunk 0..15
#pragma unroll
                for (int cf = 0; cf < 16; ++cf) {
                    int r = cf * 16 + lr;
                    bf16x8 rB = *(const bf16x8*)(smem
                        + (((r >> 6) * 2 + (c4 >> 3)) << 13)
                        + ((r & 63) << 7)
                        + ((((c4 & 7) ^ (r & 7))) << 4));
                    acc[cf] = MFMA(pA, rB, acc[cf]);
                }
            }
            __builtin_amdgcn_s_setprio(0);
        }
    }

    // ---- epilogue: denominators in registers (lane roles match PV) ----
    float inv[4];
#pragma unroll
    for (int ri = 0; ri < 4; ++ri) {
        float v = dsum[ri];
        v += __shfl_xor(v, 1); v += __shfl_xor(v, 2);
        v += __shfl_xor(v, 4); v += __shfl_xor(v, 8);
        inv[ri] = 1.0f / v;            // den(gA, nqh*4+ri)
    }
#pragma unroll
    for (int cf = 0; cf < 16; ++cf) {
        int c = cf * 16 + lr;
#pragma unroll
        for (int ri = 0; ri < 4; ++ri) {
            int n2 = (nqh << 2) + ri;
            flat[(long)(n0 + n2) * 4096 + gA * 256 + c] = (__bf16)(acc[cf][ri] * inv[ri]);
        }
    }
}

// ---------------------------------------------------------------------------
// out(2048x256 f32) = flat(2048x4096 bf16) @ conv_w(256x4096 bf16)^T + conv_b
__launch_bounds__(256)
__global__ void conv_gemm(const __bf16* __restrict__ flat, const __bf16* __restrict__ cw,
                          const float* __restrict__ cb, float* __restrict__ out) {
    const int tid = threadIdx.x, l = tid & 63, wid = tid >> 6;
    const int n0 = (blockIdx.x >> 1) * 16;
    const int j0 = (blockIdx.x & 1) * 128 + wid * 32;
    const int lr = l & 15, lk = l >> 4;
    f32x4 acc[2] = {(f32x4){0.f, 0.f, 0.f, 0.f}, (f32x4){0.f, 0.f, 0.f, 0.f}};
#pragma unroll 4
    for (int k0 = 0; k0 < 4096; k0 += 32) {
        bf16x8 af = *(const bf16x8*)(flat + (long)(n0 + lr) * 4096 + k0 + lk * 8);
#pragma unroll
        for (int cf = 0; cf < 2; ++cf) {
            bf16x8 bfr = *(const bf16x8*)(cw + (long)(j0 + cf * 16 + lr) * 4096 + k0 + lk * 8);
            acc[cf] = MFMA(af, bfr, acc[cf]);
        }
    }
#pragma unroll
    for (int cf = 0; cf < 2; ++cf) {
        int j = j0 + cf * 16 + lr;
        float bv = cb[j];
#pragma unroll
        for (int ri = 0; ri < 4; ++ri)
            out[(n0 + lk * 4 + ri) * 256 + j] = acc[cf][ri] + bv;
    }
}

// ---------------------------------------------------------------------------
extern "C" void kernel_launch(void* const* d_in, const int* in_sizes, int n_in,
                              void* d_out, int out_size, void* d_ws, size_t ws_size,
                              hipStream_t stream) {
    const float* roi  = (const float*)d_in[0];
    const float* pe   = (const float*)d_in[1];
    const float* fc1w = (const float*)d_in[2];
    const float* fc1b = (const float*)d_in[3];
    const float* fc2w = (const float*)d_in[4];
    const float* fc2b = (const float*)d_in[5];
    const float* fc3w = (const float*)d_in[6];
    const float* fc3b = (const float*)d_in[7];
    const float* cw   = (const float*)d_in[8];
    const float* cb   = (const float*)d_in[9];
    float* out = (float*)d_out;

    unsigned char* ws = (unsigned char*)d_ws;
    __bf16* roiT   = (__bf16*)(ws);                         // 1 MiB
    __bf16* convwb = (__bf16*)(ws + (1ull  << 20));         // 2 MiB
    __bf16* qb     = (__bf16*)(ws + (3ull  << 20));         // 4 MiB
    __bf16* kb     = (__bf16*)(ws + (7ull  << 20));         // 4 MiB
    __bf16* flat   = (__bf16*)(ws + (11ull << 20));         // 16 MiB
    __bf16* wg     = (__bf16*)(ws + (27ull << 20));         // 128 MiB

    prep_all<<<9856, 256, 0, stream>>>(roi, pe, fc1w, fc1b, fc2w, fc2b,
                                       fc3w, fc3b, cw,
                                       roiT, convwb, qb, kb, wg);
    relation_attn<<<512, 256, 0, stream>>>(wg, qb, kb, roiT, flat);
    conv_gemm<<<256, 256, 0, stream>>>(flat, convwb, cb, out);
}